// Round 6
// baseline (409.444 us; speedup 1.0000x reference)
//
#include <hip/hip_runtime.h>
#include <math.h>

#define BATCH 64
#define IC 2048
// J = M = N = 16
#define NIW 2               // i's per wave, W resident in VGPRs (128 regs, asm-pinned)
#define NW  8               // waves per block (512 threads)
#define NIB (NIW * NW)      // 16 i's per block
#define NGB (IC / NIB)      // 128 i-groups
#define BSPL 2              // b-split: each block does 32 b's
#define NBB (BATCH / BSPL)  // 32
// grid = NGB * BSPL = 256 blocks = 1/CU, 8 waves = 2/SIMD

// Non-rematerializable W load: compiler cannot sink/remat inline asm, so the
// fragment MUST stay register-resident across the b-loop (R2/R4 failure mode).
// offset is in BYTES; n-stride of W[i,j,n,m] is 16 floats = 64 B  (R5 bug:
// used n*256 -> OOB fault at j=15, last i).
#define WLOAD(dst, base, off) \
    asm volatile("global_load_dwordx4 %0, %1, off offset:" #off \
                 : "=&v"(dst) : "v"(base) : "memory")

__device__ __forceinline__ const float4* uniform_ptr(const float* p) {
    // u addresses are wave-uniform; readfirstlane lets LLVM prove it and
    // emit scalar loads (u -> SGPRs), freeing VGPRs.
    uint64_t v = (uint64_t)(uintptr_t)p;
    uint32_t lo = __builtin_amdgcn_readfirstlane((uint32_t)v);
    uint32_t hi = __builtin_amdgcn_readfirstlane((uint32_t)(v >> 32));
    return (const float4*)(uintptr_t)(((uint64_t)hi << 32) | lo);
}

// Lane map: j = lane&15 (softmax dim), mg = lane>>4 (m = 4mg..4mg+3 as float4).
// m-reduce = shfl_xor 16,32 ; softmax-over-j = shfl_xor 1,2,4,8.
template <bool FIRST>
__global__ __launch_bounds__(512, 2) void pass_kernel(
    const float* __restrict__ Wt,      // [IC, 16, 16, 16]  (i, j, n, m)
    const float* __restrict__ inp,     // [BATCH, IC, 16]
    const float* __restrict__ vcum,    // [BATCH, 16, 16]   (b, j, m)
    float* __restrict__ partial)       // [NGB, BATCH, 256]
{
    const int tid  = threadIdx.x;
    const int wave = tid >> 6;
    const int lane = tid & 63;
    const int j    = lane & 15;
    const int mg   = lane >> 4;
    const int bi   = blockIdx.x;
    const int g    = (bi & 7) | ((bi >> 4) << 3);   // twins bi, bi+8 -> same XCD
    const int half = (bi >> 3) & 1;
    const int b0   = half * NBB;
    const int ibase = g * NIB + wave * NIW;

    // block-shared accumulator, lane-contiguous layout: [bloc][lane + 64*c]
    __shared__ float lacc[NBB * 256];   // 32 KB
    for (int t = tid; t < NBB * 64; t += 512)
        *(float4*)&lacc[t * 4] = make_float4(0.f, 0.f, 0.f, 0.f);

    // ---- asm-pinned resident W fragments: w[n] = W[i, j, n, 4mg..4mg+3] ----
    // byte offset: i*16384 + j*1024 + n*64 + mg*16 ; max = exactly W end.
    const float* wb0 = Wt + (size_t)ibase * 4096 + j * 256 + mg * 4;
    const float* wb1 = wb0 + 4096;
    float4 w0[16], w1[16];
    WLOAD(w0[0],  wb0, 0);   WLOAD(w0[1],  wb0, 64);
    WLOAD(w0[2],  wb0, 128); WLOAD(w0[3],  wb0, 192);
    WLOAD(w0[4],  wb0, 256); WLOAD(w0[5],  wb0, 320);
    WLOAD(w0[6],  wb0, 384); WLOAD(w0[7],  wb0, 448);
    WLOAD(w0[8],  wb0, 512); WLOAD(w0[9],  wb0, 576);
    WLOAD(w0[10], wb0, 640); WLOAD(w0[11], wb0, 704);
    WLOAD(w0[12], wb0, 768); WLOAD(w0[13], wb0, 832);
    WLOAD(w0[14], wb0, 896); WLOAD(w0[15], wb0, 960);
    WLOAD(w1[0],  wb1, 0);   WLOAD(w1[1],  wb1, 64);
    WLOAD(w1[2],  wb1, 128); WLOAD(w1[3],  wb1, 192);
    WLOAD(w1[4],  wb1, 256); WLOAD(w1[5],  wb1, 320);
    WLOAD(w1[6],  wb1, 384); WLOAD(w1[7],  wb1, 448);
    WLOAD(w1[8],  wb1, 512); WLOAD(w1[9],  wb1, 576);
    WLOAD(w1[10], wb1, 640); WLOAD(w1[11], wb1, 704);
    WLOAD(w1[12], wb1, 768); WLOAD(w1[13], wb1, 832);
    WLOAD(w1[14], wb1, 896); WLOAD(w1[15], wb1, 960);
    asm volatile("s_waitcnt vmcnt(0)" ::: "memory");

    __syncthreads();   // lacc zeros visible (also drains all counters)

    const int bst = (wave * 4) & (NBB - 1);   // stagger waves across b
    int bloc = bst;
    // prefetch b-iteration 0: u covers both i's (128 B contiguous, wave-uniform)
    const float4* up = uniform_ptr(inp + ((size_t)(b0 + bloc) * IC + ibase) * 16);
    float4 u[8];
#pragma unroll
    for (int q = 0; q < 8; ++q) u[q] = up[q];
    float4 vcn;
    if (!FIRST)
        vcn = *(const float4*)(vcum + (b0 + bloc) * 256 + j * 16 + mg * 4);

    for (int bb = 0; bb < NBB; ++bb) {
        const int cb = bloc;
        float4 uc[8];
#pragma unroll
        for (int q = 0; q < 8; ++q) uc[q] = u[q];
        const float4 vcc = vcn;
        // issue next-b loads before compute (SW pipeline)
        bloc = (bst + bb + 1) & (NBB - 1);
        if (bb + 1 < NBB) {
            const float4* upn = uniform_ptr(inp + ((size_t)(b0 + bloc) * IC + ibase) * 16);
#pragma unroll
            for (int q = 0; q < 8; ++q) u[q] = upn[q];
            if (!FIRST)
                vcn = *(const float4*)(vcum + (b0 + bloc) * 256 + j * 16 + mg * 4);
        }

        float4 h0 = make_float4(0.f, 0.f, 0.f, 0.f);
        float4 h1 = make_float4(0.f, 0.f, 0.f, 0.f);
#define ACC4(H, W, S)                                                   \
        (H).x = fmaf((W).x, (S), (H).x); (H).y = fmaf((W).y, (S), (H).y); \
        (H).z = fmaf((W).z, (S), (H).z); (H).w = fmaf((W).w, (S), (H).w);
        ACC4(h0, w0[0],  uc[0].x) ACC4(h0, w0[1],  uc[0].y)
        ACC4(h0, w0[2],  uc[0].z) ACC4(h0, w0[3],  uc[0].w)
        ACC4(h0, w0[4],  uc[1].x) ACC4(h0, w0[5],  uc[1].y)
        ACC4(h0, w0[6],  uc[1].z) ACC4(h0, w0[7],  uc[1].w)
        ACC4(h0, w0[8],  uc[2].x) ACC4(h0, w0[9],  uc[2].y)
        ACC4(h0, w0[10], uc[2].z) ACC4(h0, w0[11], uc[2].w)
        ACC4(h0, w0[12], uc[3].x) ACC4(h0, w0[13], uc[3].y)
        ACC4(h0, w0[14], uc[3].z) ACC4(h0, w0[15], uc[3].w)
        ACC4(h1, w1[0],  uc[4].x) ACC4(h1, w1[1],  uc[4].y)
        ACC4(h1, w1[2],  uc[4].z) ACC4(h1, w1[3],  uc[4].w)
        ACC4(h1, w1[4],  uc[5].x) ACC4(h1, w1[5],  uc[5].y)
        ACC4(h1, w1[6],  uc[5].z) ACC4(h1, w1[7],  uc[5].w)
        ACC4(h1, w1[8],  uc[6].x) ACC4(h1, w1[9],  uc[6].y)
        ACC4(h1, w1[10], uc[6].z) ACC4(h1, w1[11], uc[6].w)
        ACC4(h1, w1[12], uc[7].x) ACC4(h1, w1[13], uc[7].y)
        ACC4(h1, w1[14], uc[7].z) ACC4(h1, w1[15], uc[7].w)
#undef ACC4

        float4 a;
        if (FIRST) {
            a.x = h0.x + h1.x; a.y = h0.y + h1.y;
            a.z = h0.z + h1.z; a.w = h0.w + h1.w;
        } else {
            // logits for both i's (independent routing chains, ILP-friendly)
            float t0 = h0.x * vcc.x + h0.y * vcc.y + h0.z * vcc.z + h0.w * vcc.w;
            float t1 = h1.x * vcc.x + h1.y * vcc.y + h1.z * vcc.z + h1.w * vcc.w;
            t0 += __shfl_xor(t0, 16); t1 += __shfl_xor(t1, 16);
            t0 += __shfl_xor(t0, 32); t1 += __shfl_xor(t1, 32);
            const float e0 = __expf(t0), e1 = __expf(t1);
            float s0 = e0, s1 = e1;
            s0 += __shfl_xor(s0, 1); s1 += __shfl_xor(s1, 1);
            s0 += __shfl_xor(s0, 2); s1 += __shfl_xor(s1, 2);
            s0 += __shfl_xor(s0, 4); s1 += __shfl_xor(s1, 4);
            s0 += __shfl_xor(s0, 8); s1 += __shfl_xor(s1, 8);
            const float c0 = e0 * __builtin_amdgcn_rcpf(s0);
            const float c1 = e1 * __builtin_amdgcn_rcpf(s1);
            a.x = fmaf(c0, h0.x, c1 * h1.x);
            a.y = fmaf(c0, h0.y, c1 * h1.y);
            a.z = fmaf(c0, h0.z, c1 * h1.z);
            a.w = fmaf(c0, h0.w, c1 * h1.w);
        }
        // conflict-free (2-way) LDS atomic accumulate: addr = lane + 64*c
        float* lp = &lacc[cb * 256 + lane];
        atomicAdd(lp,       a.x);
        atomicAdd(lp + 64,  a.y);
        atomicAdd(lp + 128, a.z);
        atomicAdd(lp + 192, a.w);
    }
    __syncthreads();

    // write partial in standard [b][j*16+m] layout, coalesced float4 stores.
    // stored el(e): e=4q+c -> lds addr = ob*256 + (q&3)*16 + (q>>2) + 64*c
#pragma unroll
    for (int r = 0; r < (NBB * 64) / 512; ++r) {   // 4 iters
        const int idx = r * 512 + tid;
        const int ob  = idx >> 6;
        const int q   = idx & 63;
        const int base = ob * 256 + ((q & 3) << 4) + (q >> 2);
        float4 v;
        v.x = lacc[base];
        v.y = lacc[base + 64];
        v.z = lacc[base + 128];
        v.w = lacc[base + 192];
        *(float4*)(partial + ((size_t)g * BATCH + b0 + ob) * 256 + q * 4) = v;
    }
}

// Grid = BATCH*4 blocks of 64 threads. Reduce over NGB groups, squash
// (m-sum intra-wave: e = j*16+m, shfl 1,2,4,8), update vcum / write out.
__global__ __launch_bounds__(64) void reduce_squash(
    const float* __restrict__ partial, float* __restrict__ vcum,
    float* __restrict__ out, int stage)
{
    const int b = blockIdx.x >> 2;
    const int q = blockIdx.x & 3;
    const int e = q * 64 + threadIdx.x;
    const float* p = partial + (size_t)b * 256 + e;
    float s = 0.0f;
#pragma unroll 8
    for (int gi = 0; gi < NGB; ++gi)
        s += p[(size_t)gi * BATCH * 256];
    if (stage == 0) s *= (1.0f / 16.0f);   // uniform c = 1/16 on iteration 0

    float n2 = s * s;
    n2 += __shfl_xor(n2, 1);
    n2 += __shfl_xor(n2, 2);
    n2 += __shfl_xor(n2, 4);
    n2 += __shfl_xor(n2, 8);
    const float scale = n2 / ((1.0f + n2) * sqrtf(n2 + 1e-8f));
    const float v = scale * s;

    const int o = b * 256 + e;
    if (stage == 0)      vcum[o] = v;
    else if (stage == 1) vcum[o] += v;
    else                 out[o] = v;
}

extern "C" void kernel_launch(void* const* d_in, const int* in_sizes, int n_in,
                              void* d_out, int out_size, void* d_ws, size_t ws_size,
                              hipStream_t stream) {
    const float* inp = (const float*)d_in[0];   // [64, 2048, 16]
    const float* Wt  = (const float*)d_in[1];   // [2048, 16, 16, 16]
    float* out = (float*)d_out;                 // [64, 16, 16]
    float* partial = (float*)d_ws;              // NGB*BATCH*256 floats = 8.4 MB
    float* vcum = partial + (size_t)NGB * BATCH * 256;  // 64 KB

    const dim3 gp(NGB * BSPL), bp(512);
    const dim3 gr(BATCH * 4), br(64);

    // iter 0: c uniform -> s0 ; v0 = squash(s0/16); vcum = v0
    pass_kernel<true><<<gp, bp, 0, stream>>>(Wt, inp, nullptr, partial);
    reduce_squash<<<gr, br, 0, stream>>>(partial, vcum, out, 0);
    // iter 1: logits from vcum=v0 -> s1 ; vcum += v1
    pass_kernel<false><<<gp, bp, 0, stream>>>(Wt, inp, vcum, partial);
    reduce_squash<<<gr, br, 0, stream>>>(partial, vcum, out, 1);
    // iter 2: logits from vcum=v0+v1 -> s2 ; out = squash(s2)
    pass_kernel<false><<<gp, bp, 0, stream>>>(Wt, inp, vcum, partial);
    reduce_squash<<<gr, br, 0, stream>>>(partial, vcum, out, 2);
}